// Round 2
// baseline (23632.642 us; speedup 1.0000x reference)
//
#include <hip/hip_runtime.h>
#include <hip/hip_bf16.h>
#include <cstddef>

// Problem constants (match reference)
#define LNUM 2
#define DDIM 2048
#define HNUM 16
#define HDIM 128
#define FFDIM 5632
#define RNK 16
#define BB 4
#define SS 512
#define LORA_SCALE 1.4f
#define INV_TEMP 20.0f   // 1/0.05

#define BSROWS (BB * SS)          // 2048
#define BSD ((size_t)BSROWS * DDIM)   // 4,194,304
#define BSFF ((size_t)BSROWS * FFDIM) // 11,534,336

// ---------------------------------------------------------------------------
// Embedding gather: h[b,s,:] = emb[ids[b,s],:]
__global__ __launch_bounds__(256) void embed_kernel(const int* __restrict__ ids,
                                                    const float* __restrict__ emb,
                                                    float* __restrict__ H) {
    int bs = blockIdx.x;
    int id = ids[bs];
    const float4* src = (const float4*)(emb + (size_t)id * DDIM);
    float4* dst = (float4*)(H + (size_t)bs * DDIM);
    for (int i = threadIdx.x; i < DDIM / 4; i += 256) dst[i] = src[i];
}

// ---------------------------------------------------------------------------
// RMSNorm: y = x * rsqrt(mean(x^2)+1e-6) * w   (one block per row)
__global__ __launch_bounds__(256) void rmsnorm_kernel(const float* __restrict__ X,
                                                      const float* __restrict__ w,
                                                      float* __restrict__ Y) {
    __shared__ float red[256];
    int row = blockIdx.x;
    const float* x = X + (size_t)row * DDIM;
    float ss = 0.f;
    for (int d = threadIdx.x; d < DDIM; d += 256) { float v = x[d]; ss += v * v; }
    red[threadIdx.x] = ss; __syncthreads();
    for (int s = 128; s > 0; s >>= 1) {
        if (threadIdx.x < s) red[threadIdx.x] += red[threadIdx.x + s];
        __syncthreads();
    }
    float scale = rsqrtf(red[0] / (float)DDIM + 1e-6f);
    float* y = Y + (size_t)row * DDIM;
    for (int d = threadIdx.x; d < DDIM; d += 256) y[d] = x[d] * scale * w[d];
}

// ---------------------------------------------------------------------------
// Tiled fp32 GEMM: C[N,M] = X[N,K] @ W[K,M], all row-major.
// 128x128 tile, 256 threads, 8x8 per thread, BK=16,
// register-staged double buffering for the global->LDS path.
#define TM 128
#define TN 128
#define TKK 16
__global__ __launch_bounds__(256) void gemm_kernel(const float* __restrict__ X,
                                                   const float* __restrict__ W,
                                                   float* __restrict__ C,
                                                   int N, int K, int M) {
    __shared__ float As[TKK][TM + 4];   // [16][132] — k-major, padded
    __shared__ float Bs[TKK][TN];       // [16][128]
    int tid = threadIdx.x;
    int tx = tid & 15, ty = tid >> 4;
    int row0 = blockIdx.y * TM, col0 = blockIdx.x * TN;

    // A-tile: 128 rows x 16 cols = 512 float4 units; unit u: rr=u>>2, kq=u&3
    int a_rr0 = tid >> 2;                 // unit u = tid
    int a_kq  = tid & 3;                  // same for both units
    int a_rr1 = (tid + 256) >> 2;         // unit u = tid + 256
    // B-tile: 16 rows x 128 cols = 512 float4 units; unit u: kr=u>>5, cq=u&31
    int b_kr0 = tid >> 5;
    int b_cq  = tid & 31;
    int b_kr1 = (tid + 256) >> 5;

    const float* Xa0 = X + (size_t)(row0 + a_rr0) * K + a_kq * 4;
    const float* Xa1 = X + (size_t)(row0 + a_rr1) * K + a_kq * 4;
    const float* Wb0 = W + (size_t)b_kr0 * M + col0 + b_cq * 4;
    const float* Wb1 = W + (size_t)b_kr1 * M + col0 + b_cq * 4;

    // prologue: stage k0 = 0
    float4 a0 = *(const float4*)Xa0;
    float4 a1 = *(const float4*)Xa1;
    float4 b0 = *(const float4*)Wb0;
    float4 b1 = *(const float4*)Wb1;

    float acc[8][8] = {};

    for (int k0 = 0; k0 < K; k0 += TKK) {
        // write staged registers into LDS
        As[a_kq * 4 + 0][a_rr0] = a0.x;
        As[a_kq * 4 + 1][a_rr0] = a0.y;
        As[a_kq * 4 + 2][a_rr0] = a0.z;
        As[a_kq * 4 + 3][a_rr0] = a0.w;
        As[a_kq * 4 + 0][a_rr1] = a1.x;
        As[a_kq * 4 + 1][a_rr1] = a1.y;
        As[a_kq * 4 + 2][a_rr1] = a1.z;
        As[a_kq * 4 + 3][a_rr1] = a1.w;
        *(float4*)&Bs[b_kr0][b_cq * 4] = b0;
        *(float4*)&Bs[b_kr1][b_cq * 4] = b1;
        __syncthreads();

        // prefetch next tile into registers (lands during compute below)
        if (k0 + TKK < K) {
            a0 = *(const float4*)(Xa0 + k0 + TKK);
            a1 = *(const float4*)(Xa1 + k0 + TKK);
            b0 = *(const float4*)(Wb0 + (size_t)(k0 + TKK) * M);
            b1 = *(const float4*)(Wb1 + (size_t)(k0 + TKK) * M);
        }

#pragma unroll
        for (int kk = 0; kk < TKK; ++kk) {
            float ar[8], br[8];
            *(float4*)&ar[0] = *(const float4*)&As[kk][ty * 8];
            *(float4*)&ar[4] = *(const float4*)&As[kk][ty * 8 + 4];
            *(float4*)&br[0] = *(const float4*)&Bs[kk][tx * 8];
            *(float4*)&br[4] = *(const float4*)&Bs[kk][tx * 8 + 4];
#pragma unroll
            for (int i = 0; i < 8; ++i)
#pragma unroll
                for (int j = 0; j < 8; ++j) acc[i][j] += ar[i] * br[j];
        }
        __syncthreads();
    }

#pragma unroll
    for (int i = 0; i < 8; ++i) {
        float* crow = C + (size_t)(row0 + ty * 8 + i) * M + col0 + tx * 8;
        float4 c0 = {acc[i][0], acc[i][1], acc[i][2], acc[i][3]};
        float4 c1 = {acc[i][4], acc[i][5], acc[i][6], acc[i][7]};
        *(float4*)&crow[0] = c0;
        *(float4*)&crow[4] = c1;
    }
}

// ---------------------------------------------------------------------------
// Narrow GEMM for LoRA A: T[N,16] = X[N,K] @ A[K,16]. One block per row.
__global__ __launch_bounds__(256) void gemm16_kernel(const float* __restrict__ X,
                                                     const float* __restrict__ A,
                                                     float* __restrict__ T, int K) {
    __shared__ float part[16][17];
    int n = blockIdx.x;
    int c = threadIdx.x & 15;
    int ks = threadIdx.x >> 4;
    int kper = K / 16;
    const float* xr = X + (size_t)n * K + (size_t)ks * kper;
    const float* ac = A + (size_t)ks * kper * 16 + c;
    float acc = 0.f;
    for (int k = 0; k < kper; ++k) acc += xr[k] * ac[(size_t)k * 16];
    part[ks][c] = acc; __syncthreads();
    if (threadIdx.x < 16) {
        float s = 0.f;
#pragma unroll
        for (int i = 0; i < 16; ++i) s += part[i][threadIdx.x];
        T[(size_t)n * 16 + threadIdx.x] = s;
    }
}

// ---------------------------------------------------------------------------
// C[n,:] += 1.4 * T[n,:16] @ Bm[16,M]     (one block per row)
__global__ __launch_bounds__(256) void lora_add_kernel(float* __restrict__ C,
                                                       const float* __restrict__ T,
                                                       const float* __restrict__ Bm,
                                                       int M) {
    __shared__ float t[16];
    int n = blockIdx.x;
    if (threadIdx.x < 16) t[threadIdx.x] = T[(size_t)n * 16 + threadIdx.x];
    __syncthreads();
    for (int m = threadIdx.x; m < M; m += 256) {
        float acc = 0.f;
#pragma unroll
        for (int r = 0; r < 16; ++r) acc += t[r] * Bm[(size_t)r * M + m];
        C[(size_t)n * M + m] += LORA_SCALE * acc;
    }
}

// H[n,:] += C[n,:] + 1.4 * T[n,:16] @ Bm[16,M]
__global__ __launch_bounds__(256) void lora_add_residual_kernel(float* __restrict__ H,
                                                                const float* __restrict__ C,
                                                                const float* __restrict__ T,
                                                                const float* __restrict__ Bm,
                                                                int M) {
    __shared__ float t[16];
    int n = blockIdx.x;
    if (threadIdx.x < 16) t[threadIdx.x] = T[(size_t)n * 16 + threadIdx.x];
    __syncthreads();
    for (int m = threadIdx.x; m < M; m += 256) {
        float acc = 0.f;
#pragma unroll
        for (int r = 0; r < 16; ++r) acc += t[r] * Bm[(size_t)r * M + m];
        H[(size_t)n * M + m] += C[(size_t)n * M + m] + LORA_SCALE * acc;
    }
}

// ---------------------------------------------------------------------------
// RoPE in-place on [B,S,H,HD]. grid = B*S*H blocks of 64 threads.
__global__ __launch_bounds__(64) void rope_kernel(float* __restrict__ X) {
    int j = threadIdx.x;                 // 0..63 (half dim)
    int idx = blockIdx.x;                // ((b*S + s)*H + h)
    int s = (idx / HNUM) % SS;
    float* p = X + (size_t)idx * HDIM;
    float freq = powf(10000.f, -(float)j / 64.f);
    float ang = (float)s * freq;
    float c = cosf(ang), sn = sinf(ang);
    float x1 = p[j], x2 = p[j + 64];
    p[j] = x1 * c - x2 * sn;
    p[j + 64] = x1 * sn + x2 * c;
}

// ---------------------------------------------------------------------------
// Attention: one block per (b,h,qi). 128 threads.
__global__ __launch_bounds__(128) void attn_kernel(const float* __restrict__ Q,
                                                   const float* __restrict__ Kt,
                                                   const float* __restrict__ Vt,
                                                   const int* __restrict__ mask,
                                                   float* __restrict__ O) {
    __shared__ float qs[HDIM];
    __shared__ float sc[SS];
    __shared__ float red[128];
    int t = threadIdx.x;
    int qi = blockIdx.x % SS;
    int h = (blockIdx.x / SS) % HNUM;
    int b = blockIdx.x / (SS * HNUM);
    const float* qp = Q + (((size_t)b * SS + qi) * HNUM + h) * HDIM;
    qs[t] = qp[t];
    __syncthreads();
    const float inv = 0.08838834764831845f;  // 1/sqrt(128)
    for (int k = t; k < SS; k += 128) {
        const float* kp = Kt + (((size_t)b * SS + k) * HNUM + h) * HDIM;
        float dot = 0.f;
        for (int d = 0; d < HDIM; ++d) dot += qs[d] * kp[d];
        bool valid = (k <= qi) && (mask[b * SS + k] > 0);
        sc[k] = dot * inv + (valid ? 0.f : -1e9f);
    }
    __syncthreads();
    float m = -1e30f;
    for (int k = t; k < SS; k += 128) m = fmaxf(m, sc[k]);
    red[t] = m; __syncthreads();
    for (int s2 = 64; s2 > 0; s2 >>= 1) {
        if (t < s2) red[t] = fmaxf(red[t], red[t + s2]);
        __syncthreads();
    }
    m = red[0]; __syncthreads();
    float sum = 0.f;
    for (int k = t; k < SS; k += 128) { float e = expf(sc[k] - m); sc[k] = e; sum += e; }
    red[t] = sum; __syncthreads();
    for (int s2 = 64; s2 > 0; s2 >>= 1) {
        if (t < s2) red[t] += red[t + s2];
        __syncthreads();
    }
    float denom = red[0];
    float o = 0.f;  // thread t owns dim d=t
    for (int k = 0; k < SS; ++k)
        o += sc[k] * Vt[(((size_t)b * SS + k) * HNUM + h) * HDIM + t];
    O[(((size_t)b * SS + qi) * HNUM + h) * HDIM + t] = o / denom;
}

// ---------------------------------------------------------------------------
// G = silu(G) * U elementwise (float4 grid-stride)
__global__ __launch_bounds__(256) void silu_mul_kernel(float* __restrict__ G,
                                                       const float* __restrict__ U,
                                                       size_t n4) {
    for (size_t i = (size_t)blockIdx.x * 256 + threadIdx.x; i < n4;
         i += (size_t)gridDim.x * 256) {
        float4 g = ((const float4*)G)[i];
        float4 u = ((const float4*)U)[i];
        float4 r;
        r.x = g.x / (1.f + expf(-g.x)) * u.x;
        r.y = g.y / (1.f + expf(-g.y)) * u.y;
        r.z = g.z / (1.f + expf(-g.z)) * u.z;
        r.w = g.w / (1.f + expf(-g.w)) * u.w;
        ((float4*)G)[i] = r;
    }
}

// ---------------------------------------------------------------------------
// Rep extraction + L2 normalize. One block per batch row.
__global__ __launch_bounds__(256) void reps_kernel(const float* __restrict__ Xn,
                                                   const int* __restrict__ mask,
                                                   float* __restrict__ reps) {
    __shared__ float red[256];
    __shared__ int sidx;
    int b = blockIdx.x;
    int ls = 0;
    for (int s = threadIdx.x; s < SS; s += 256) ls += mask[b * SS + s];
    red[threadIdx.x] = (float)ls; __syncthreads();
    for (int s2 = 128; s2 > 0; s2 >>= 1) {
        if (threadIdx.x < s2) red[threadIdx.x] += red[threadIdx.x + s2];
        __syncthreads();
    }
    if (threadIdx.x == 0) {
        int lastsum = 0;
        for (int bb = 0; bb < BB; ++bb) lastsum += mask[bb * SS + SS - 1];
        int lensum = (int)(red[0] + 0.5f);
        sidx = (lastsum == BB) ? (SS - 1) : (lensum - 1);
    }
    __syncthreads();
    const float* xr = Xn + ((size_t)b * SS + sidx) * DDIM;
    float ss = 0.f;
    for (int d = threadIdx.x; d < DDIM; d += 256) { float v = xr[d]; ss += v * v; }
    red[threadIdx.x] = ss; __syncthreads();
    for (int s2 = 128; s2 > 0; s2 >>= 1) {
        if (threadIdx.x < s2) red[threadIdx.x] += red[threadIdx.x + s2];
        __syncthreads();
    }
    float invn = rsqrtf(red[0]);
    for (int d = threadIdx.x; d < DDIM; d += 256)
        reps[(size_t)b * DDIM + d] = xr[d] * invn;
}

// ---------------------------------------------------------------------------
// InfoNCE loss from the two 4x2048 rep matrices.
__global__ __launch_bounds__(256) void loss_kernel(const float* __restrict__ RQ,
                                                   const float* __restrict__ RP,
                                                   float* __restrict__ out) {
    __shared__ float red[256];
    __shared__ float sims[BB][BB];
    for (int p = 0; p < BB * BB; ++p) {
        int i = p / BB, j = p % BB;
        float acc = 0.f;
        for (int d = threadIdx.x; d < DDIM; d += 256)
            acc += RQ[(size_t)i * DDIM + d] * RP[(size_t)j * DDIM + d];
        red[threadIdx.x] = acc; __syncthreads();
        for (int s2 = 128; s2 > 0; s2 >>= 1) {
            if (threadIdx.x < s2) red[threadIdx.x] += red[threadIdx.x + s2];
            __syncthreads();
        }
        if (threadIdx.x == 0) sims[i][j] = red[0] * INV_TEMP;
        __syncthreads();
    }
    if (threadIdx.x == 0) {
        float loss = 0.f;
        for (int i = 0; i < BB; ++i) {
            float m = sims[i][0];
            for (int j = 1; j < BB; ++j) m = fmaxf(m, sims[i][j]);
            float s = 0.f;
            for (int j = 0; j < BB; ++j) s += expf(sims[i][j] - m);
            loss += -(sims[i][i] - m - logf(s));
        }
        out[0] = loss / (float)BB;
    }
}

// ---------------------------------------------------------------------------
extern "C" void kernel_launch(void* const* d_in, const int* in_sizes, int n_in,
                              void* d_out, int out_size, void* d_ws, size_t ws_size,
                              hipStream_t stream) {
    const int* ids_t = (const int*)d_in[0];
    const int* mask_t = (const int*)d_in[1];
    const int* ids_m = (const int*)d_in[2];
    const int* mask_m = (const int*)d_in[3];
    const float* emb = (const float*)d_in[4];
    const float* ln1 = (const float*)d_in[5];
    const float* ln2 = (const float*)d_in[6];
    const float* lnf = (const float*)d_in[7];
    const float* Wq = (const float*)d_in[8];
    const float* Aq = (const float*)d_in[9];
    const float* Bq = (const float*)d_in[10];
    const float* Wk = (const float*)d_in[11];
    const float* Ak = (const float*)d_in[12];
    const float* Bk = (const float*)d_in[13];
    const float* Wv = (const float*)d_in[14];
    const float* Av = (const float*)d_in[15];
    const float* Bv = (const float*)d_in[16];
    const float* Wo = (const float*)d_in[17];
    const float* Ao = (const float*)d_in[18];
    const float* Bo = (const float*)d_in[19];
    const float* Wg = (const float*)d_in[20];
    const float* Ag = (const float*)d_in[21];
    const float* Bg = (const float*)d_in[22];
    const float* Wu = (const float*)d_in[23];
    const float* Au = (const float*)d_in[24];
    const float* Bu = (const float*)d_in[25];
    const float* Wd = (const float*)d_in[26];
    const float* Ad = (const float*)d_in[27];
    const float* Bd = (const float*)d_in[28];

    float* ws = (float*)d_ws;
    float* h    = ws;
    float* x    = ws + 1 * BSD;
    float* qb   = ws + 2 * BSD;
    float* kb   = ws + 3 * BSD;
    float* vb   = ws + 4 * BSD;
    float* ob   = ws + 5 * BSD;
    float* proj = ws + 6 * BSD;
    float* gbuf = ws + 7 * BSD;
    float* ubuf = gbuf + BSFF;
    float* T    = ubuf + BSFF;
    float* repsq = T + (size_t)BSROWS * 16;
    float* repsp = repsq + BB * DDIM;

    auto gemm = [&](const float* X, const float* W, float* C, int K, int M) {
        dim3 grid(M / TN, BSROWS / TM);
        hipLaunchKernelGGL(gemm_kernel, grid, dim3(256), 0, stream, X, W, C,
                           BSROWS, K, M);
    };
    auto lora_proj = [&](const float* X, const float* Wm, const float* Am,
                         const float* Bm, float* C, int K, int M) {
        gemm(X, Wm, C, K, M);
        hipLaunchKernelGGL(gemm16_kernel, dim3(BSROWS), dim3(256), 0, stream, X, Am, T, K);
        hipLaunchKernelGGL(lora_add_kernel, dim3(BSROWS), dim3(256), 0, stream, C, T, Bm, M);
    };
    auto lora_proj_res = [&](const float* X, const float* Wm, const float* Am,
                             const float* Bm, float* Hb, float* C, int K, int M) {
        gemm(X, Wm, C, K, M);
        hipLaunchKernelGGL(gemm16_kernel, dim3(BSROWS), dim3(256), 0, stream, X, Am, T, K);
        hipLaunchKernelGGL(lora_add_residual_kernel, dim3(BSROWS), dim3(256), 0,
                           stream, Hb, C, T, Bm, M);
    };

    for (int enc = 0; enc < 2; ++enc) {
        const int* ids = enc == 0 ? ids_t : ids_m;
        const int* mask = enc == 0 ? mask_t : mask_m;
        float* reps = enc == 0 ? repsq : repsp;

        hipLaunchKernelGGL(embed_kernel, dim3(BSROWS), dim3(256), 0, stream, ids, emb, h);

        for (int l = 0; l < LNUM; ++l) {
            size_t oDD = (size_t)l * DDIM * DDIM;
            size_t oDR = (size_t)l * DDIM * RNK;
            size_t oRD = (size_t)l * RNK * DDIM;
            size_t oDF = (size_t)l * DDIM * FFDIM;
            size_t oRF = (size_t)l * RNK * FFDIM;
            size_t oFD = (size_t)l * FFDIM * DDIM;
            size_t oFR = (size_t)l * FFDIM * RNK;

            hipLaunchKernelGGL(rmsnorm_kernel, dim3(BSROWS), dim3(256), 0, stream,
                               h, ln1 + (size_t)l * DDIM, x);
            lora_proj(x, Wq + oDD, Aq + oDR, Bq + oRD, qb, DDIM, DDIM);
            lora_proj(x, Wk + oDD, Ak + oDR, Bk + oRD, kb, DDIM, DDIM);
            lora_proj(x, Wv + oDD, Av + oDR, Bv + oRD, vb, DDIM, DDIM);
            hipLaunchKernelGGL(rope_kernel, dim3(BB * SS * HNUM), dim3(64), 0, stream, qb);
            hipLaunchKernelGGL(rope_kernel, dim3(BB * SS * HNUM), dim3(64), 0, stream, kb);
            hipLaunchKernelGGL(attn_kernel, dim3(BB * HNUM * SS), dim3(128), 0,
                               stream, qb, kb, vb, mask, ob);
            lora_proj_res(ob, Wo + oDD, Ao + oDR, Bo + oRD, h, proj, DDIM, DDIM);

            hipLaunchKernelGGL(rmsnorm_kernel, dim3(BSROWS), dim3(256), 0, stream,
                               h, ln2 + (size_t)l * DDIM, x);
            lora_proj(x, Wg + oDF, Ag + oDR, Bg + oRF, gbuf, DDIM, FFDIM);
            lora_proj(x, Wu + oDF, Au + oDR, Bu + oRF, ubuf, DDIM, FFDIM);
            hipLaunchKernelGGL(silu_mul_kernel, dim3(2048), dim3(256), 0, stream,
                               gbuf, ubuf, BSFF / 4);
            lora_proj_res(gbuf, Wd + oFD, Ad + oFR, Bd + oRD, h, proj, FFDIM, DDIM);
        }
        hipLaunchKernelGGL(rmsnorm_kernel, dim3(BSROWS), dim3(256), 0, stream, h, lnf, x);
        hipLaunchKernelGGL(reps_kernel, dim3(BB), dim3(256), 0, stream, x, mask, reps);
    }
    hipLaunchKernelGGL(loss_kernel, dim3(1), dim3(256), 0, stream,
                       repsq, repsp, (float*)d_out);
}

// Round 3
// 8549.497 us; speedup vs baseline: 2.7642x; 2.7642x over previous
//
#include <hip/hip_runtime.h>
#include <hip/hip_bf16.h>
#include <cstddef>
#include <cstdint>

// Problem constants (match reference)
#define LNUM 2
#define DDIM 2048
#define HNUM 16
#define HDIM 128
#define FFDIM 5632
#define RNK 16
#define BB 4
#define SS 512
#define LORA_SCALE 1.4f
#define INV_TEMP 20.0f   // 1/0.05

#define BSROWS (BB * SS)              // 2048
#define BSD ((size_t)BSROWS * DDIM)   // 4,194,304
#define BSFF ((size_t)BSROWS * FFDIM) // 11,534,336
#define MAXXE ((size_t)BSROWS * FFDIM) // max X elements (2048x5632)
#define MAXWE ((size_t)FFDIM * DDIM)   // max W elements

typedef __attribute__((ext_vector_type(8))) short bf16x8;
typedef __attribute__((ext_vector_type(4))) float f32x4;

__device__ __forceinline__ unsigned short f2bf(float f) {
    unsigned u = __float_as_uint(f);
    unsigned r = (u + 0x7FFFu + ((u >> 16) & 1u)) >> 16;   // RN-even
    return (unsigned short)r;
}
__device__ __forceinline__ float bf2f(unsigned short h) {
    return __uint_as_float(((unsigned)h) << 16);
}

// ---------------------------------------------------------------------------
// Embedding gather: h[b,s,:] = emb[ids[b,s],:]
__global__ __launch_bounds__(256) void embed_kernel(const int* __restrict__ ids,
                                                    const float* __restrict__ emb,
                                                    float* __restrict__ H) {
    int bs = blockIdx.x;
    int id = ids[bs];
    const float4* src = (const float4*)(emb + (size_t)id * DDIM);
    float4* dst = (float4*)(H + (size_t)bs * DDIM);
    for (int i = threadIdx.x; i < DDIM / 4; i += 256) dst[i] = src[i];
}

// ---------------------------------------------------------------------------
// RMSNorm: y = x * rsqrt(mean(x^2)+1e-6) * w   (one block per row)
__global__ __launch_bounds__(256) void rmsnorm_kernel(const float* __restrict__ X,
                                                      const float* __restrict__ w,
                                                      float* __restrict__ Y) {
    __shared__ float red[256];
    int row = blockIdx.x;
    const float* x = X + (size_t)row * DDIM;
    float ss = 0.f;
    for (int d = threadIdx.x; d < DDIM; d += 256) { float v = x[d]; ss += v * v; }
    red[threadIdx.x] = ss; __syncthreads();
    for (int s = 128; s > 0; s >>= 1) {
        if (threadIdx.x < s) red[threadIdx.x] += red[threadIdx.x + s];
        __syncthreads();
    }
    float scale = rsqrtf(red[0] / (float)DDIM + 1e-6f);
    float* y = Y + (size_t)row * DDIM;
    for (int d = threadIdx.x; d < DDIM; d += 256) y[d] = x[d] * scale * w[d];
}

// ---------------------------------------------------------------------------
// Split-bf16 conversion: hi = bf16(x), lo = bf16(x - hi).  n4 = n/4.
__global__ __launch_bounds__(256) void convx_kernel(const float* __restrict__ X,
                                                    unsigned short* __restrict__ hi,
                                                    unsigned short* __restrict__ lo,
                                                    size_t n4) {
    for (size_t i = (size_t)blockIdx.x * 256 + threadIdx.x; i < n4;
         i += (size_t)gridDim.x * 256) {
        float4 v = ((const float4*)X)[i];
        ushort4 hv, lv;
        hv.x = f2bf(v.x); lv.x = f2bf(v.x - bf2f(hv.x));
        hv.y = f2bf(v.y); lv.y = f2bf(v.y - bf2f(hv.y));
        hv.z = f2bf(v.z); lv.z = f2bf(v.z - bf2f(hv.z));
        hv.w = f2bf(v.w); lv.w = f2bf(v.w - bf2f(hv.w));
        ((ushort4*)hi)[i] = hv;
        ((ushort4*)lo)[i] = lv;
    }
}

// ---------------------------------------------------------------------------
// Weight convert + transpose: W fp32 [K][M] -> Thi/Tlo bf16 [M][K].
// grid (M/32, K/32), 256 threads.
__global__ __launch_bounds__(256) void wconvt_kernel(const float* __restrict__ W,
                                                     unsigned short* __restrict__ Thi,
                                                     unsigned short* __restrict__ Tlo,
                                                     int K, int M) {
    __shared__ float tl[32][33];
    int t = threadIdx.x;
    int tr = t >> 5, tc = t & 31;
    int k0 = blockIdx.y * 32, m0 = blockIdx.x * 32;
#pragma unroll
    for (int i = 0; i < 4; ++i)
        tl[tr + i * 8][tc] = W[(size_t)(k0 + tr + i * 8) * M + m0 + tc];
    __syncthreads();
#pragma unroll
    for (int i = 0; i < 4; ++i) {
        float v = tl[tc][tr + i * 8];
        int mo = m0 + tr + i * 8, ko = k0 + tc;
        unsigned short hb = f2bf(v);
        Thi[(size_t)mo * K + ko] = hb;
        Tlo[(size_t)mo * K + ko] = f2bf(v - bf2f(hb));
    }
}

// ---------------------------------------------------------------------------
// MFMA split-bf16 GEMM: C[2048][M] = X[2048][K] @ W[K][M]
// Inputs pre-converted: Xhi/Xlo row-major [2048][K]; Whi/Wlo TRANSPOSED [M][K].
// C = Xh*Wh + Xh*Wl + Xl*Wh (fp32 accum). 128x128 tile, BK=64, 4 waves (2x2).
__global__ __launch_bounds__(256) void gemm_mfma_kernel(
    const unsigned short* __restrict__ Xhi, const unsigned short* __restrict__ Xlo,
    const unsigned short* __restrict__ Whi, const unsigned short* __restrict__ Wlo,
    float* __restrict__ C, int K, int M) {
    __shared__ unsigned short sAh[128 * 64];
    __shared__ unsigned short sAl[128 * 64];
    __shared__ unsigned short sBh[128 * 64];
    __shared__ unsigned short sBl[128 * 64];
    int t = threadIdx.x;
    int lane = t & 63, wave = t >> 6;
    int wm = wave >> 1, wn = wave & 1;
    int m0 = blockIdx.y * 128, n0 = blockIdx.x * 128;
    int lr = lane & 15, lk = lane >> 4;   // fragment row / k-group

    const unsigned short* XhA = Xhi + (size_t)m0 * K;
    const unsigned short* XlA = Xlo + (size_t)m0 * K;
    const unsigned short* WhB = Whi + (size_t)n0 * K;
    const unsigned short* WlB = Wlo + (size_t)n0 * K;

    f32x4 acc[4][4] = {};

    for (int k0 = 0; k0 < K; k0 += 64) {
        // stage 4 tiles of [128 rows][64 k] bf16, chunk-XOR swizzled
#pragma unroll
        for (int i = 0; i < 4; ++i) {
            int idx = i * 256 + t;
            int rr = idx >> 3, cc = idx & 7;              // row, 16B-chunk
            int lo = rr * 64 + ((cc ^ (rr & 7)) << 3);    // element offset in LDS
            size_t ga = (size_t)rr * K + k0 + (cc << 3);  // element offset in global
            *(int4*)(sAh + lo) = *(const int4*)(XhA + ga);
            *(int4*)(sAl + lo) = *(const int4*)(XlA + ga);
            *(int4*)(sBh + lo) = *(const int4*)(WhB + ga);
            *(int4*)(sBl + lo) = *(const int4*)(WlB + ga);
        }
        __syncthreads();
#pragma unroll
        for (int kh = 0; kh < 2; ++kh) {
            bf16x8 ah[4], al[4], bh[4], bl[4];
#pragma unroll
            for (int f = 0; f < 4; ++f) {
                int ra = wm * 64 + f * 16 + lr;
                int ca = (kh * 4 + lk) ^ (ra & 7);
                ah[f] = *(const bf16x8*)(sAh + ra * 64 + (ca << 3));
                al[f] = *(const bf16x8*)(sAl + ra * 64 + (ca << 3));
                int rb = wn * 64 + f * 16 + lr;
                int cb = (kh * 4 + lk) ^ (rb & 7);
                bh[f] = *(const bf16x8*)(sBh + rb * 64 + (cb << 3));
                bl[f] = *(const bf16x8*)(sBl + rb * 64 + (cb << 3));
            }
#pragma unroll
            for (int fm = 0; fm < 4; ++fm)
#pragma unroll
                for (int fn = 0; fn < 4; ++fn) {
                    acc[fm][fn] = __builtin_amdgcn_mfma_f32_16x16x32_bf16(
                        ah[fm], bh[fn], acc[fm][fn], 0, 0, 0);
                    acc[fm][fn] = __builtin_amdgcn_mfma_f32_16x16x32_bf16(
                        ah[fm], bl[fn], acc[fm][fn], 0, 0, 0);
                    acc[fm][fn] = __builtin_amdgcn_mfma_f32_16x16x32_bf16(
                        al[fm], bh[fn], acc[fm][fn], 0, 0, 0);
                }
        }
        __syncthreads();
    }
    // epilogue: C/D layout (verified): col = lane&15, row = (lane>>4)*4 + j
#pragma unroll
    for (int fm = 0; fm < 4; ++fm)
#pragma unroll
        for (int fn = 0; fn < 4; ++fn) {
            int col = n0 + wn * 64 + fn * 16 + lr;
#pragma unroll
            for (int j = 0; j < 4; ++j) {
                int row = m0 + wm * 64 + fm * 16 + lk * 4 + j;
                C[(size_t)row * M + col] = acc[fm][fn][j];
            }
        }
}

// ---------------------------------------------------------------------------
// Narrow GEMM for LoRA A: T[N,16] = X[N,K] @ A[K,16]. One block per row.
__global__ __launch_bounds__(256) void gemm16_kernel(const float* __restrict__ X,
                                                     const float* __restrict__ A,
                                                     float* __restrict__ T, int K) {
    __shared__ float part[16][17];
    int n = blockIdx.x;
    int c = threadIdx.x & 15;
    int ks = threadIdx.x >> 4;
    int kper = K / 16;
    const float* xr = X + (size_t)n * K + (size_t)ks * kper;
    const float* ac = A + (size_t)ks * kper * 16 + c;
    float acc = 0.f;
    for (int k = 0; k < kper; ++k) acc += xr[k] * ac[(size_t)k * 16];
    part[ks][c] = acc; __syncthreads();
    if (threadIdx.x < 16) {
        float s = 0.f;
#pragma unroll
        for (int i = 0; i < 16; ++i) s += part[i][threadIdx.x];
        T[(size_t)n * 16 + threadIdx.x] = s;
    }
}

// ---------------------------------------------------------------------------
// C[n,:] += 1.4 * T[n,:16] @ Bm[16,M]
__global__ __launch_bounds__(256) void lora_add_kernel(float* __restrict__ C,
                                                       const float* __restrict__ T,
                                                       const float* __restrict__ Bm,
                                                       int M) {
    __shared__ float tv[16];
    int n = blockIdx.x;
    if (threadIdx.x < 16) tv[threadIdx.x] = T[(size_t)n * 16 + threadIdx.x];
    __syncthreads();
    for (int m = threadIdx.x; m < M; m += 256) {
        float acc = 0.f;
#pragma unroll
        for (int r = 0; r < 16; ++r) acc += tv[r] * Bm[(size_t)r * M + m];
        C[(size_t)n * M + m] += LORA_SCALE * acc;
    }
}

// H[n,:] += C[n,:] + 1.4 * T[n,:16] @ Bm[16,M]
__global__ __launch_bounds__(256) void lora_add_residual_kernel(float* __restrict__ H,
                                                                const float* __restrict__ C,
                                                                const float* __restrict__ T,
                                                                const float* __restrict__ Bm,
                                                                int M) {
    __shared__ float tv[16];
    int n = blockIdx.x;
    if (threadIdx.x < 16) tv[threadIdx.x] = T[(size_t)n * 16 + threadIdx.x];
    __syncthreads();
    for (int m = threadIdx.x; m < M; m += 256) {
        float acc = 0.f;
#pragma unroll
        for (int r = 0; r < 16; ++r) acc += tv[r] * Bm[(size_t)r * M + m];
        H[(size_t)n * M + m] += C[(size_t)n * M + m] + LORA_SCALE * acc;
    }
}

// ---------------------------------------------------------------------------
// RoPE in-place on [B,S,H,HD]. grid = B*S*H blocks of 64 threads.
__global__ __launch_bounds__(64) void rope_kernel(float* __restrict__ X) {
    int j = threadIdx.x;                 // 0..63 (half dim)
    int idx = blockIdx.x;                // ((b*S + s)*H + h)
    int s = (idx / HNUM) % SS;
    float* p = X + (size_t)idx * HDIM;
    float freq = powf(10000.f, -(float)j / 64.f);
    float ang = (float)s * freq;
    float c = cosf(ang), sn = sinf(ang);
    float x1 = p[j], x2 = p[j + 64];
    p[j] = x1 * c - x2 * sn;
    p[j + 64] = x1 * sn + x2 * c;
}

// ---------------------------------------------------------------------------
// Flash attention: block = (b, h, 32-row q-tile), 256 threads.
// LDS chunk-XOR swizzle: float4-chunk slot = c4 ^ (((r>>2)&7)<<2).
__global__ __launch_bounds__(256) void fattn_kernel(const float* __restrict__ Q,
                                                    const float* __restrict__ Kt,
                                                    const float* __restrict__ Vt,
                                                    const int* __restrict__ mask,
                                                    float* __restrict__ O) {
    __shared__ float Qs[32 * 128];
    __shared__ float Ks[32 * 128];
    __shared__ float Vs[32 * 128];
    __shared__ float Ps[32][33];
    int t = threadIdx.x;
    int qt = blockIdx.x & 15;
    int h = (blockIdx.x >> 4) & 15;
    int b = blockIdx.x >> 8;
    int q0 = qt * 32;
    int qr = t >> 3;          // q-row 0..31 (both phases)
    int kc4 = t & 7;          // QK: key group (4 keys); PV: d-group (16 dims)

    // stage Q tile
#pragma unroll
    for (int i = 0; i < 4; ++i) {
        int idx = i * 256 + t;
        int r = idx >> 5, c4 = idx & 31;
        int slot = c4 ^ (((r >> 2) & 7) << 2);
        float4 v = *(const float4*)(Q + ((((size_t)b * SS + q0 + r) * HNUM + h) * HDIM) + c4 * 4);
        *(float4*)(Qs + r * 128 + slot * 4) = v;
    }
    const float inv = 0.08838834764831845f;  // 1/sqrt(128)
    float m_run = -1e30f, l_run = 0.f;
    float4 o4[4] = {};
    int qi = q0 + qr;

    for (int kt = 0; kt <= qt; ++kt) {
        int k0 = kt * 32;
        __syncthreads();  // protect Ks/Vs from previous iteration's readers
#pragma unroll
        for (int i = 0; i < 4; ++i) {
            int idx = i * 256 + t;
            int r = idx >> 5, c4 = idx & 31;
            int slot = c4 ^ (((r >> 2) & 7) << 2);
            size_t gb = (((size_t)b * SS + k0 + r) * HNUM + h) * HDIM + c4 * 4;
            *(float4*)(Ks + r * 128 + slot * 4) = *(const float4*)(Kt + gb);
            *(float4*)(Vs + r * 128 + slot * 4) = *(const float4*)(Vt + gb);
        }
        __syncthreads();
        // QK^T: thread -> (qr, keys k0 + kc4*4 + j)
        float s[4] = {0.f, 0.f, 0.f, 0.f};
#pragma unroll 4
        for (int d4 = 0; d4 < 32; ++d4) {
            float4 q4 = *(const float4*)(Qs + qr * 128 + (d4 ^ (((qr >> 2) & 7) << 2)) * 4);
#pragma unroll
            for (int j = 0; j < 4; ++j) {
                int kr = kc4 * 4 + j;
                float4 k4 = *(const float4*)(Ks + kr * 128 + (d4 ^ (((kr >> 2) & 7) << 2)) * 4);
                s[j] += q4.x * k4.x + q4.y * k4.y + q4.z * k4.z + q4.w * k4.w;
            }
        }
        float pmax = -1e30f;
#pragma unroll
        for (int j = 0; j < 4; ++j) {
            int kg = k0 + kc4 * 4 + j;
            bool valid = (kg <= qi) && (mask[b * SS + kg] > 0);
            s[j] = s[j] * inv + (valid ? 0.f : -1e9f);
            pmax = fmaxf(pmax, s[j]);
        }
#pragma unroll
        for (int w = 1; w < 8; w <<= 1) pmax = fmaxf(pmax, __shfl_xor(pmax, w));
        float m_new = fmaxf(m_run, pmax);
        float alpha = expf(m_run - m_new);
        float rowsum = 0.f;
#pragma unroll
        for (int j = 0; j < 4; ++j) {
            s[j] = expf(s[j] - m_new);
            rowsum += s[j];
        }
#pragma unroll
        for (int w = 1; w < 8; w <<= 1) rowsum += __shfl_xor(rowsum, w);
        l_run = l_run * alpha + rowsum;
        m_run = m_new;
#pragma unroll
        for (int j = 0; j < 4; ++j) Ps[qr][kc4 * 4 + j] = s[j];
        __syncthreads();
        // PV: thread -> (qr, dims kc4*16 .. +15); rescale O by alpha
#pragma unroll
        for (int j4 = 0; j4 < 4; ++j4) {
            o4[j4].x *= alpha; o4[j4].y *= alpha; o4[j4].z *= alpha; o4[j4].w *= alpha;
        }
        for (int kk = 0; kk < 32; ++kk) {
            float p = Ps[qr][kk];
            int sw = ((kk >> 2) & 7) << 2;
#pragma unroll
            for (int j4 = 0; j4 < 4; ++j4) {
                float4 v4 = *(const float4*)(Vs + kk * 128 + ((kc4 * 4 + j4) ^ sw) * 4);
                o4[j4].x += p * v4.x; o4[j4].y += p * v4.y;
                o4[j4].z += p * v4.z; o4[j4].w += p * v4.w;
            }
        }
    }
    float rl = 1.f / l_run;
    size_t ob = (((size_t)b * SS + q0 + qr) * HNUM + h) * HDIM + kc4 * 16;
#pragma unroll
    for (int j4 = 0; j4 < 4; ++j4) {
        float4 r;
        r.x = o4[j4].x * rl; r.y = o4[j4].y * rl;
        r.z = o4[j4].z * rl; r.w = o4[j4].w * rl;
        *(float4*)(O + ob + j4 * 4) = r;
    }
}

// ---------------------------------------------------------------------------
// G = silu(G) * U elementwise (float4 grid-stride)
__global__ __launch_bounds__(256) void silu_mul_kernel(float* __restrict__ G,
                                                       const float* __restrict__ U,
                                                       size_t n4) {
    for (size_t i = (size_t)blockIdx.x * 256 + threadIdx.x; i < n4;
         i += (size_t)gridDim.x * 256) {
        float4 g = ((const float4*)G)[i];
        float4 u = ((const float4*)U)[i];
        float4 r;
        r.x = g.x / (1.f + expf(-g.x)) * u.x;
        r.y = g.y / (1.f + expf(-g.y)) * u.y;
        r.z = g.z / (1.f + expf(-g.z)) * u.z;
        r.w = g.w / (1.f + expf(-g.w)) * u.w;
        ((float4*)G)[i] = r;
    }
}

// ---------------------------------------------------------------------------
// Rep extraction + L2 normalize. One block per batch row.
__global__ __launch_bounds__(256) void reps_kernel(const float* __restrict__ Xn,
                                                   const int* __restrict__ mask,
                                                   float* __restrict__ reps) {
    __shared__ float red[256];
    __shared__ int sidx;
    int b = blockIdx.x;
    int ls = 0;
    for (int s = threadIdx.x; s < SS; s += 256) ls += mask[b * SS + s];
    red[threadIdx.x] = (float)ls; __syncthreads();
    for (int s2 = 128; s2 > 0; s2 >>= 1) {
        if (threadIdx.x < s2) red[threadIdx.x] += red[threadIdx.x + s2];
        __syncthreads();
    }
    if (threadIdx.x == 0) {
        int lastsum = 0;
        for (int bb = 0; bb < BB; ++bb) lastsum += mask[bb * SS + SS - 1];
        int lensum = (int)(red[0] + 0.5f);
        sidx = (lastsum == BB) ? (SS - 1) : (lensum - 1);
    }
    __syncthreads();
    const float* xr = Xn + ((size_t)b * SS + sidx) * DDIM;
    float ss = 0.f;
    for (int d = threadIdx.x; d < DDIM; d += 256) { float v = xr[d]; ss += v * v; }
    red[threadIdx.x] = ss; __syncthreads();
    for (int s2 = 128; s2 > 0; s2 >>= 1) {
        if (threadIdx.x < s2) red[threadIdx.x] += red[threadIdx.x + s2];
        __syncthreads();
    }
    float invn = rsqrtf(red[0]);
    for (int d = threadIdx.x; d < DDIM; d += 256)
        reps[(size_t)b * DDIM + d] = xr[d] * invn;
}

// ---------------------------------------------------------------------------
// InfoNCE loss from the two 4x2048 rep matrices.
__global__ __launch_bounds__(256) void loss_kernel(const float* __restrict__ RQ,
                                                   const float* __restrict__ RP,
                                                   float* __restrict__ out) {
    __shared__ float red[256];
    __shared__ float sims[BB][BB];
    for (int p = 0; p < BB * BB; ++p) {
        int i = p / BB, j = p % BB;
        float acc = 0.f;
        for (int d = threadIdx.x; d < DDIM; d += 256)
            acc += RQ[(size_t)i * DDIM + d] * RP[(size_t)j * DDIM + d];
        red[threadIdx.x] = acc; __syncthreads();
        for (int s2 = 128; s2 > 0; s2 >>= 1) {
            if (threadIdx.x < s2) red[threadIdx.x] += red[threadIdx.x + s2];
            __syncthreads();
        }
        if (threadIdx.x == 0) sims[i][j] = red[0] * INV_TEMP;
        __syncthreads();
    }
    if (threadIdx.x == 0) {
        float loss = 0.f;
        for (int i = 0; i < BB; ++i) {
            float m = sims[i][0];
            for (int j = 1; j < BB; ++j) m = fmaxf(m, sims[i][j]);
            float s = 0.f;
            for (int j = 0; j < BB; ++j) s += expf(sims[i][j] - m);
            loss += -(sims[i][i] - m - logf(s));
        }
        out[0] = loss / (float)BB;
    }
}

// ---------------------------------------------------------------------------
extern "C" void kernel_launch(void* const* d_in, const int* in_sizes, int n_in,
                              void* d_out, int out_size, void* d_ws, size_t ws_size,
                              hipStream_t stream) {
    const int* ids_t = (const int*)d_in[0];
    const int* mask_t = (const int*)d_in[1];
    const int* ids_m = (const int*)d_in[2];
    const int* mask_m = (const int*)d_in[3];
    const float* emb = (const float*)d_in[4];
    const float* ln1 = (const float*)d_in[5];
    const float* ln2 = (const float*)d_in[6];
    const float* lnf = (const float*)d_in[7];
    const float* Wq = (const float*)d_in[8];
    const float* Aq = (const float*)d_in[9];
    const float* Bq = (const float*)d_in[10];
    const float* Wk = (const float*)d_in[11];
    const float* Ak = (const float*)d_in[12];
    const float* Bk = (const float*)d_in[13];
    const float* Wv = (const float*)d_in[14];
    const float* Av = (const float*)d_in[15];
    const float* Bv = (const float*)d_in[16];
    const float* Wo = (const float*)d_in[17];
    const float* Ao = (const float*)d_in[18];
    const float* Bo = (const float*)d_in[19];
    const float* Wg = (const float*)d_in[20];
    const float* Ag = (const float*)d_in[21];
    const float* Bg = (const float*)d_in[22];
    const float* Wu = (const float*)d_in[23];
    const float* Au = (const float*)d_in[24];
    const float* Bu = (const float*)d_in[25];
    const float* Wd = (const float*)d_in[26];
    const float* Ad = (const float*)d_in[27];
    const float* Bd = (const float*)d_in[28];

    float* ws = (float*)d_ws;
    float* h    = ws;
    float* x    = ws + 1 * BSD;
    float* qb   = ws + 2 * BSD;
    float* kb   = ws + 3 * BSD;
    float* vb   = ws + 4 * BSD;
    float* ob   = ws + 5 * BSD;
    float* proj = ws + 6 * BSD;
    float* gbuf = ws + 7 * BSD;
    float* ubuf = gbuf + BSFF;
    float* T    = ubuf + BSFF;
    float* repsq = T + (size_t)BSROWS * 16;
    float* repsp = repsq + BB * DDIM;
    unsigned short* xhi = (unsigned short*)(repsp + BB * DDIM);
    unsigned short* xlo = xhi + MAXXE;
    unsigned short* whi = xlo + MAXXE;
    unsigned short* wlo = whi + MAXWE;

    auto conv_x = [&](const float* Xf, size_t n) {
        hipLaunchKernelGGL(convx_kernel, dim3(1024), dim3(256), 0, stream,
                           Xf, xhi, xlo, n / 4);
    };
    auto mfma_proj = [&](const float* Wf, int K, int M, float* C) {
        hipLaunchKernelGGL(wconvt_kernel, dim3(M / 32, K / 32), dim3(256), 0, stream,
                           Wf, whi, wlo, K, M);
        hipLaunchKernelGGL(gemm_mfma_kernel, dim3(M / 128, BSROWS / 128), dim3(256),
                           0, stream, xhi, xlo, whi, wlo, C, K, M);
    };
    auto lora_tail = [&](const float* Xf, const float* Am, const float* Bm,
                         float* C, int K, int M) {
        hipLaunchKernelGGL(gemm16_kernel, dim3(BSROWS), dim3(256), 0, stream, Xf, Am, T, K);
        hipLaunchKernelGGL(lora_add_kernel, dim3(BSROWS), dim3(256), 0, stream, C, T, Bm, M);
    };
    auto lora_tail_res = [&](const float* Xf, const float* Am, const float* Bm,
                             float* Hb, float* C, int K, int M) {
        hipLaunchKernelGGL(gemm16_kernel, dim3(BSROWS), dim3(256), 0, stream, Xf, Am, T, K);
        hipLaunchKernelGGL(lora_add_residual_kernel, dim3(BSROWS), dim3(256), 0,
                           stream, Hb, C, T, Bm, M);
    };

    for (int enc = 0; enc < 2; ++enc) {
        const int* ids = enc == 0 ? ids_t : ids_m;
        const int* mask = enc == 0 ? mask_t : mask_m;
        float* reps = enc == 0 ? repsq : repsp;

        hipLaunchKernelGGL(embed_kernel, dim3(BSROWS), dim3(256), 0, stream, ids, emb, h);

        for (int l = 0; l < LNUM; ++l) {
            size_t oDD = (size_t)l * DDIM * DDIM;
            size_t oDR = (size_t)l * DDIM * RNK;
            size_t oRD = (size_t)l * RNK * DDIM;
            size_t oDF = (size_t)l * DDIM * FFDIM;
            size_t oRF = (size_t)l * RNK * FFDIM;
            size_t oFD = (size_t)l * FFDIM * DDIM;
            size_t oFR = (size_t)l * FFDIM * RNK;

            hipLaunchKernelGGL(rmsnorm_kernel, dim3(BSROWS), dim3(256), 0, stream,
                               h, ln1 + (size_t)l * DDIM, x);
            conv_x(x, BSD);
            mfma_proj(Wq + oDD, DDIM, DDIM, qb);
            lora_tail(x, Aq + oDR, Bq + oRD, qb, DDIM, DDIM);
            mfma_proj(Wk + oDD, DDIM, DDIM, kb);
            lora_tail(x, Ak + oDR, Bk + oRD, kb, DDIM, DDIM);
            mfma_proj(Wv + oDD, DDIM, DDIM, vb);
            lora_tail(x, Av + oDR, Bv + oRD, vb, DDIM, DDIM);

            hipLaunchKernelGGL(rope_kernel, dim3(BB * SS * HNUM), dim3(64), 0, stream, qb);
            hipLaunchKernelGGL(rope_kernel, dim3(BB * SS * HNUM), dim3(64), 0, stream, kb);
            hipLaunchKernelGGL(fattn_kernel, dim3(BB * HNUM * (SS / 32)), dim3(256),
                               0, stream, qb, kb, vb, mask, ob);

            conv_x(ob, BSD);
            mfma_proj(Wo + oDD, DDIM, DDIM, proj);
            lora_tail_res(ob, Ao + oDR, Bo + oRD, h, proj, DDIM, DDIM);

            hipLaunchKernelGGL(rmsnorm_kernel, dim3(BSROWS), dim3(256), 0, stream,
                               h, ln2 + (size_t)l * DDIM, x);
            conv_x(x, BSD);
            mfma_proj(Wg + oDF, DDIM, FFDIM, gbuf);
            lora_tail(x, Ag + oDR, Bg + oRF, gbuf, DDIM, FFDIM);
            mfma_proj(Wu + oDF, DDIM, FFDIM, ubuf);
            lora_tail(x, Au + oDR, Bu + oRF, ubuf, DDIM, FFDIM);

            hipLaunchKernelGGL(silu_mul_kernel, dim3(2048), dim3(256), 0, stream,
                               gbuf, ubuf, BSFF / 4);
            conv_x(gbuf, BSFF);
            mfma_proj(Wd + oFD, FFDIM, DDIM, proj);
            lora_tail_res(gbuf, Ad + oFR, Bd + oRD, h, proj, FFDIM, DDIM);
        }
        hipLaunchKernelGGL(rmsnorm_kernel, dim3(BSROWS), dim3(256), 0, stream, h, lnf, x);
        hipLaunchKernelGGL(reps_kernel, dim3(BB), dim3(256), 0, stream, x, mask, reps);
    }
    hipLaunchKernelGGL(loss_kernel, dim3(1), dim3(256), 0, stream,
                       repsq, repsp, (float*)d_out);
}

// Round 7
// 8085.600 us; speedup vs baseline: 2.9228x; 1.0574x over previous
//
#include <hip/hip_runtime.h>
#include <hip/hip_bf16.h>
#include <cstddef>
#include <cstdint>

// Problem constants (match reference)
#define LNUM 2
#define DDIM 2048
#define HNUM 16
#define HDIM 128
#define FFDIM 5632
#define RNK 16
#define BB 4
#define SS 512
#define LORA_SCALE 1.4f
#define INV_TEMP 20.0f   // 1/0.05

#define BSROWS (BB * SS)              // 2048
#define BSD ((size_t)BSROWS * DDIM)   // 4,194,304
#define BSFF ((size_t)BSROWS * FFDIM) // 11,534,336
#define MAXXE ((size_t)BSROWS * FFDIM) // max X elements (2048x5632)
#define MAXWE ((size_t)FFDIM * DDIM)   // max W elements

typedef __attribute__((ext_vector_type(8))) short bf16x8;
typedef __attribute__((ext_vector_type(4))) float f32x4;

__device__ __forceinline__ unsigned short f2bf(float f) {
    unsigned u = __float_as_uint(f);
    unsigned r = (u + 0x7FFFu + ((u >> 16) & 1u)) >> 16;   // RN-even
    return (unsigned short)r;
}
__device__ __forceinline__ float bf2f(unsigned short h) {
    return __uint_as_float(((unsigned)h) << 16);
}

// async global->LDS, 16B per lane. LDS base must be wave-uniform; HW writes
// lane L to ldsbase + L*16.
__device__ __forceinline__ void gll16(const unsigned short* g, unsigned short* l) {
    __builtin_amdgcn_global_load_lds(
        (const __attribute__((address_space(1))) unsigned int*)g,
        (__attribute__((address_space(3))) unsigned int*)l, 16, 0, 0);
}

// ---------------------------------------------------------------------------
// Embedding gather: h[b,s,:] = emb[ids[b,s],:]
__global__ __launch_bounds__(256) void embed_kernel(const int* __restrict__ ids,
                                                    const float* __restrict__ emb,
                                                    float* __restrict__ H) {
    int bs = blockIdx.x;
    int id = ids[bs];
    const float4* src = (const float4*)(emb + (size_t)id * DDIM);
    float4* dst = (float4*)(H + (size_t)bs * DDIM);
    for (int i = threadIdx.x; i < DDIM / 4; i += 256) dst[i] = src[i];
}

// ---------------------------------------------------------------------------
// RMSNorm (plain): y = x * rsqrt(mean(x^2)+1e-6) * w   (one block per row)
__global__ __launch_bounds__(256) void rmsnorm_kernel(const float* __restrict__ X,
                                                      const float* __restrict__ w,
                                                      float* __restrict__ Y) {
    __shared__ float red[256];
    int row = blockIdx.x;
    const float* x = X + (size_t)row * DDIM;
    float ss = 0.f;
    for (int d = threadIdx.x; d < DDIM; d += 256) { float v = x[d]; ss += v * v; }
    red[threadIdx.x] = ss; __syncthreads();
    for (int s = 128; s > 0; s >>= 1) {
        if (threadIdx.x < s) red[threadIdx.x] += red[threadIdx.x + s];
        __syncthreads();
    }
    float scale = rsqrtf(red[0] / (float)DDIM + 1e-6f);
    float* y = Y + (size_t)row * DDIM;
    for (int d = threadIdx.x; d < DDIM; d += 256) y[d] = x[d] * scale * w[d];
}

// RMSNorm fused with split-bf16 conversion: y fp32 + (hi,lo) bf16.
__global__ __launch_bounds__(256) void rmsnorm_conv_kernel(
    const float* __restrict__ X, const float* __restrict__ w,
    float* __restrict__ Y, unsigned short* __restrict__ hi,
    unsigned short* __restrict__ lo) {
    __shared__ float red[256];
    int row = blockIdx.x;
    const float* x = X + (size_t)row * DDIM;
    float ss = 0.f;
    for (int d = threadIdx.x; d < DDIM; d += 256) { float v = x[d]; ss += v * v; }
    red[threadIdx.x] = ss; __syncthreads();
    for (int s = 128; s > 0; s >>= 1) {
        if (threadIdx.x < s) red[threadIdx.x] += red[threadIdx.x + s];
        __syncthreads();
    }
    float scale = rsqrtf(red[0] / (float)DDIM + 1e-6f);
    size_t base = (size_t)row * DDIM;
    for (int d = threadIdx.x; d < DDIM; d += 256) {
        float y = x[d] * scale * w[d];
        Y[base + d] = y;
        unsigned short hb = f2bf(y);
        hi[base + d] = hb;
        lo[base + d] = f2bf(y - bf2f(hb));
    }
}

// ---------------------------------------------------------------------------
// Weight convert + transpose: W fp32 [K][M] -> Thi/Tlo bf16 [M][K].
// grid (M/32, K/32), 256 threads.
__global__ __launch_bounds__(256) void wconvt_kernel(const float* __restrict__ W,
                                                     unsigned short* __restrict__ Thi,
                                                     unsigned short* __restrict__ Tlo,
                                                     int K, int M) {
    __shared__ float tl[32][33];
    int t = threadIdx.x;
    int tr = t >> 5, tc = t & 31;
    int k0 = blockIdx.y * 32, m0 = blockIdx.x * 32;
#pragma unroll
    for (int i = 0; i < 4; ++i)
        tl[tr + i * 8][tc] = W[(size_t)(k0 + tr + i * 8) * M + m0 + tc];
    __syncthreads();
#pragma unroll
    for (int i = 0; i < 4; ++i) {
        float v = tl[tc][tr + i * 8];
        int mo = m0 + tr + i * 8, ko = k0 + tc;
        unsigned short hb = f2bf(v);
        Thi[(size_t)mo * K + ko] = hb;
        Tlo[(size_t)mo * K + ko] = f2bf(v - bf2f(hb));
    }
}

// ---------------------------------------------------------------------------
// MFMA split-bf16 GEMM: C[2048][M] = X[2048][K] @ W[K][M]
// Xhi/Xlo row-major [2048][K]; Whi/Wlo TRANSPOSED [M][K].
// C = Xh*Wh + Xh*Wl + Xl*Wh (fp32 accum). 128x128 tile, BK=64, 4 waves (2x2).
// Staging via global_load_lds(16B): LDS linear dest, INVERSE-swizzled global
// source (chunk cc^(rr&7)); fragment reads apply the same involution.
__global__ __launch_bounds__(256) void gemm_mfma_kernel(
    const unsigned short* __restrict__ Xhi, const unsigned short* __restrict__ Xlo,
    const unsigned short* __restrict__ Whi, const unsigned short* __restrict__ Wlo,
    float* __restrict__ C, int K, int M) {
    __shared__ unsigned short sAh[128 * 64];
    __shared__ unsigned short sAl[128 * 64];
    __shared__ unsigned short sBh[128 * 64];
    __shared__ unsigned short sBl[128 * 64];
    int t = threadIdx.x;
    int lane = t & 63, wave = t >> 6;
    int wm = wave >> 1, wn = wave & 1;
    int m0 = blockIdx.y * 128, n0 = blockIdx.x * 128;
    int lr = lane & 15, lk = lane >> 4;   // fragment row / k-group

    const unsigned short* XhA = Xhi + (size_t)m0 * K;
    const unsigned short* XlA = Xlo + (size_t)m0 * K;
    const unsigned short* WhB = Whi + (size_t)n0 * K;
    const unsigned short* WlB = Wlo + (size_t)n0 * K;

    // staging geometry: wave stages rows [wave*32, wave*32+32) of each array,
    // 4 instrs x (8 rows x 8 chunks). lane -> row-in-8 = lane>>3, slot = lane&7,
    // global chunk = slot ^ (row&7)
    int srow = lane >> 3;
    int scol = ((lane & 7) ^ srow) << 3;   // element offset within row

    f32x4 acc[4][4] = {};

    for (int k0 = 0; k0 < K; k0 += 64) {
#pragma unroll
        for (int i = 0; i < 4; ++i) {
            int rbase = wave * 32 + i * 8;
            size_t g = (size_t)(rbase + srow) * K + k0 + scol;
            int ldsoff = rbase * 64;
            gll16(XhA + g, sAh + ldsoff);
            gll16(XlA + g, sAl + ldsoff);
            gll16(WhB + g, sBh + ldsoff);
            gll16(WlB + g, sBl + ldsoff);
        }
        __syncthreads();   // drains vmcnt(0) before any wave reads LDS
#pragma unroll
        for (int kh = 0; kh < 2; ++kh) {
            bf16x8 ah[4], al[4], bh[4], bl[4];
#pragma unroll
            for (int f = 0; f < 4; ++f) {
                int ra = wm * 64 + f * 16 + lr;
                int ca = (kh * 4 + lk) ^ (ra & 7);
                ah[f] = *(const bf16x8*)(sAh + ra * 64 + (ca << 3));
                al[f] = *(const bf16x8*)(sAl + ra * 64 + (ca << 3));
                int rb = wn * 64 + f * 16 + lr;
                int cb = (kh * 4 + lk) ^ (rb & 7);
                bh[f] = *(const bf16x8*)(sBh + rb * 64 + (cb << 3));
                bl[f] = *(const bf16x8*)(sBl + rb * 64 + (cb << 3));
            }
#pragma unroll
            for (int fm = 0; fm < 4; ++fm)
#pragma unroll
                for (int fn = 0; fn < 4; ++fn) {
                    acc[fm][fn] = __builtin_amdgcn_mfma_f32_16x16x32_bf16(
                        ah[fm], bh[fn], acc[fm][fn], 0, 0, 0);
                    acc[fm][fn] = __builtin_amdgcn_mfma_f32_16x16x32_bf16(
                        ah[fm], bl[fn], acc[fm][fn], 0, 0, 0);
                    acc[fm][fn] = __builtin_amdgcn_mfma_f32_16x16x32_bf16(
                        al[fm], bh[fn], acc[fm][fn], 0, 0, 0);
                }
        }
        __syncthreads();
    }
    // epilogue: C/D layout: col = lane&15, row = (lane>>4)*4 + j
#pragma unroll
    for (int fm = 0; fm < 4; ++fm)
#pragma unroll
        for (int fn = 0; fn < 4; ++fn) {
            int col = n0 + wn * 64 + fn * 16 + lr;
#pragma unroll
            for (int j = 0; j < 4; ++j) {
                int row = m0 + wm * 64 + fm * 16 + lk * 4 + j;
                C[(size_t)row * M + col] = acc[fm][fn][j];
            }
        }
}

// ---------------------------------------------------------------------------
// Narrow GEMM for LoRA A: T[N,16] = X[N,K] @ A[K,16]. One block per row.
__global__ __launch_bounds__(256) void gemm16_kernel(const float* __restrict__ X,
                                                     const float* __restrict__ A,
                                                     float* __restrict__ T, int K) {
    __shared__ float part[16][17];
    int n = blockIdx.x;
    int c = threadIdx.x & 15;
    int ks = threadIdx.x >> 4;
    int kper = K / 16;
    const float* xr = X + (size_t)n * K + (size_t)ks * kper;
    const float* ac = A + (size_t)ks * kper * 16 + c;
    float acc = 0.f;
    for (int k = 0; k < kper; ++k) acc += xr[k] * ac[(size_t)k * 16];
    part[ks][c] = acc; __syncthreads();
    if (threadIdx.x < 16) {
        float s = 0.f;
#pragma unroll
        for (int i = 0; i < 16; ++i) s += part[i][threadIdx.x];
        T[(size_t)n * 16 + threadIdx.x] = s;
    }
}

// ---------------------------------------------------------------------------
// C[n,:] += 1.4 * T[n,:16] @ Bm[16,M]
__global__ __launch_bounds__(256) void lora_add_kernel(float* __restrict__ C,
                                                       const float* __restrict__ T,
                                                       const float* __restrict__ Bm,
                                                       int M) {
    __shared__ float tv[16];
    int n = blockIdx.x;
    if (threadIdx.x < 16) tv[threadIdx.x] = T[(size_t)n * 16 + threadIdx.x];
    __syncthreads();
    for (int m = threadIdx.x; m < M; m += 256) {
        float acc = 0.f;
#pragma unroll
        for (int r = 0; r < 16; ++r) acc += tv[r] * Bm[(size_t)r * M + m];
        C[(size_t)n * M + m] += LORA_SCALE * acc;
    }
}

// H[n,:] += C[n,:] + 1.4 * T[n,:16] @ Bm[16,M]
__global__ __launch_bounds__(256) void lora_add_residual_kernel(float* __restrict__ H,
                                                                const float* __restrict__ C,
                                                                const float* __restrict__ T,
                                                                const float* __restrict__ Bm,
                                                                int M) {
    __shared__ float tv[16];
    int n = blockIdx.x;
    if (threadIdx.x < 16) tv[threadIdx.x] = T[(size_t)n * 16 + threadIdx.x];
    __syncthreads();
    for (int m = threadIdx.x; m < M; m += 256) {
        float acc = 0.f;
#pragma unroll
        for (int r = 0; r < 16; ++r) acc += tv[r] * Bm[(size_t)r * M + m];
        H[(size_t)n * M + m] += C[(size_t)n * M + m] + LORA_SCALE * acc;
    }
}

// ---------------------------------------------------------------------------
// RoPE cos/sin table: tab[s*64+j] = {cos,sin}(s * 10000^(-j/64))
__global__ __launch_bounds__(64) void rope_table_kernel(float2* __restrict__ tab) {
    int s = blockIdx.x, j = threadIdx.x;
    float freq = powf(10000.f, -(float)j / 64.f);
    float ang = (float)s * freq;
    float2 cs;
    cs.x = cosf(ang);
    cs.y = sinf(ang);
    tab[s * 64 + j] = cs;
}

// RoPE in-place on q and k [B,S,H,HD]. grid = (B*S*H, 2) blocks of 64 threads.
__global__ __launch_bounds__(64) void rope_kernel(float* __restrict__ Xq,
                                                  float* __restrict__ Xk,
                                                  const float2* __restrict__ tab) {
    int j = threadIdx.x;                 // 0..63 (half dim)
    int idx = blockIdx.x;                // ((b*S + s)*H + h)
    int s = (idx / HNUM) % SS;
    float* p = (blockIdx.y ? Xk : Xq) + (size_t)idx * HDIM;
    float2 cs = tab[s * 64 + j];
    float x1 = p[j], x2 = p[j + 64];
    p[j] = x1 * cs.x - x2 * cs.y;
    p[j + 64] = x1 * cs.y + x2 * cs.x;
}

// ---------------------------------------------------------------------------
// Flash attention v2: block = (b, h, 32-row q-tile), 128 threads (2 waves).
// Thread t: kc4 = t&7, qrl = t>>3 (owns q-rows qrl and qrl+16).
// Per-buffer swizzles: Q slot = c4 ^ (r&7)
//                      K slot = c4 ^ ((r>>2)&7)
//                      V linear; PV thread-dims d = j4*32 + kc4*4
// Epilogue also emits split-bf16 (hi,lo) of O at the same flat index
// (O layout [((b*S+s)*H+h)*HD+d] == row-major [b*S+s][h*128+d] X layout).
__global__ __launch_bounds__(128) void fattn_kernel(const float* __restrict__ Q,
                                                    const float* __restrict__ Kt,
                                                    const float* __restrict__ Vt,
                                                    const int* __restrict__ mask,
                                                    float* __restrict__ O,
                                                    unsigned short* __restrict__ Ohi,
                                                    unsigned short* __restrict__ Olo) {
    __shared__ float Qs[32 * 128];
    __shared__ float Ks[32 * 128];
    __shared__ float Vs[32 * 128];
    __shared__ float Ps[32][33];
    int t = threadIdx.x;
    int qt = blockIdx.x & 15;
    int h = (blockIdx.x >> 4) & 15;
    int b = blockIdx.x >> 8;
    int q0 = qt * 32;
    int kc4 = t & 7;
    int qrl = t >> 3;          // 0..15
    int qsw = qrl & 7;         // == (qrl+16)&7

    // stage Q tile (32 rows x 32 float4-chunks), Q-swizzle
#pragma unroll
    for (int i = 0; i < 8; ++i) {
        int idx = i * 128 + t;
        int r = idx >> 5, c4 = idx & 31;
        int slot = c4 ^ (r & 7);
        *(float4*)(Qs + r * 128 + slot * 4) =
            *(const float4*)(Q + (((size_t)b * SS + q0 + r) * HNUM + h) * HDIM + c4 * 4);
    }
    const float inv = 0.08838834764831845f;  // 1/sqrt(128)
    float m0r = -1e30f, m1r = -1e30f, l0 = 0.f, l1 = 0.f;
    float4 o0[4] = {}, o1[4] = {};
    int qi0 = q0 + qrl, qi1 = q0 + qrl + 16;

    for (int kt = 0; kt <= qt; ++kt) {
        int k0 = kt * 32;
        __syncthreads();  // protect Ks/Vs/Ps from previous iteration's readers
#pragma unroll
        for (int i = 0; i < 8; ++i) {
            int idx = i * 128 + t;
            int r = idx >> 5, c4 = idx & 31;
            size_t gb = (((size_t)b * SS + k0 + r) * HNUM + h) * HDIM + c4 * 4;
            int kslot = c4 ^ ((r >> 2) & 7);
            *(float4*)(Ks + r * 128 + kslot * 4) = *(const float4*)(Kt + gb);
            *(float4*)(Vs + r * 128 + c4 * 4) = *(const float4*)(Vt + gb);
        }
        __syncthreads();
        // QK^T: 2 q-rows x 4 keys per thread
        float s0[4] = {}, s1[4] = {};
#pragma unroll 4
        for (int d4 = 0; d4 < 32; ++d4) {
            float4 qa = *(const float4*)(Qs + qrl * 128 + (d4 ^ qsw) * 4);
            float4 qb_ = *(const float4*)(Qs + (qrl + 16) * 128 + (d4 ^ qsw) * 4);
#pragma unroll
            for (int j = 0; j < 4; ++j) {
                int kr = kc4 * 4 + j;
                float4 k4 = *(const float4*)(Ks + kr * 128 + (d4 ^ ((kr >> 2) & 7)) * 4);
                s0[j] += qa.x * k4.x + qa.y * k4.y + qa.z * k4.z + qa.w * k4.w;
                s1[j] += qb_.x * k4.x + qb_.y * k4.y + qb_.z * k4.z + qb_.w * k4.w;
            }
        }
        float pm0 = -1e30f, pm1 = -1e30f;
#pragma unroll
        for (int j = 0; j < 4; ++j) {
            int kg = k0 + kc4 * 4 + j;
            bool km = mask[b * SS + kg] > 0;
            s0[j] = s0[j] * inv + ((kg <= qi0 && km) ? 0.f : -1e9f);
            s1[j] = s1[j] * inv + ((kg <= qi1 && km) ? 0.f : -1e9f);
            pm0 = fmaxf(pm0, s0[j]);
            pm1 = fmaxf(pm1, s1[j]);
        }
#pragma unroll
        for (int w = 1; w < 8; w <<= 1) {
            pm0 = fmaxf(pm0, __shfl_xor(pm0, w));
            pm1 = fmaxf(pm1, __shfl_xor(pm1, w));
        }
        float mn0 = fmaxf(m0r, pm0), mn1 = fmaxf(m1r, pm1);
        float a0 = expf(m0r - mn0), a1 = expf(m1r - mn1);
        float rs0 = 0.f, rs1 = 0.f;
#pragma unroll
        for (int j = 0; j < 4; ++j) {
            s0[j] = expf(s0[j] - mn0); rs0 += s0[j];
            s1[j] = expf(s1[j] - mn1); rs1 += s1[j];
        }
#pragma unroll
        for (int w = 1; w < 8; w <<= 1) {
            rs0 += __shfl_xor(rs0, w);
            rs1 += __shfl_xor(rs1, w);
        }
        l0 = l0 * a0 + rs0; m0r = mn0;
        l1 = l1 * a1 + rs1; m1r = mn1;
#pragma unroll
        for (int j = 0; j < 4; ++j) {
            Ps[qrl][kc4 * 4 + j] = s0[j];
            Ps[qrl + 16][kc4 * 4 + j] = s1[j];
        }
        __syncthreads();
        // PV: thread dims d = j4*32 + kc4*4 (+0..3)
#pragma unroll
        for (int j4 = 0; j4 < 4; ++j4) {
            o0[j4].x *= a0; o0[j4].y *= a0; o0[j4].z *= a0; o0[j4].w *= a0;
            o1[j4].x *= a1; o1[j4].y *= a1; o1[j4].z *= a1; o1[j4].w *= a1;
        }
        for (int kk = 0; kk < 32; ++kk) {
            float p0 = Ps[qrl][kk], p1 = Ps[qrl + 16][kk];
#pragma unroll
            for (int j4 = 0; j4 < 4; ++j4) {
                float4 v4 = *(const float4*)(Vs + kk * 128 + j4 * 32 + kc4 * 4);
                o0[j4].x += p0 * v4.x; o0[j4].y += p0 * v4.y;
                o0[j4].z += p0 * v4.z; o0[j4].w += p0 * v4.w;
                o1[j4].x += p1 * v4.x; o1[j4].y += p1 * v4.y;
                o1[j4].z += p1 * v4.z; o1[j4].w += p1 * v4.w;
            }
        }
    }
    float rl0 = 1.f / l0, rl1 = 1.f / l1;
    size_t ob0 = (((size_t)b * SS + qi0) * HNUM + h) * HDIM;
    size_t ob1 = (((size_t)b * SS + qi1) * HNUM + h) * HDIM;
#pragma unroll
    for (int j4 = 0; j4 < 4; ++j4) {
        float4 r0, r1;
        r0.x = o0[j4].x * rl0; r0.y = o0[j4].y * rl0;
        r0.z = o0[j4].z * rl0; r0.w = o0[j4].w * rl0;
        r1.x = o1[j4].x * rl1; r1.y = o1[j4].y * rl1;
        r1.z = o1[j4].z * rl1; r1.w = o1[j4].w * rl1;
        size_t i0 = ob0 + j4 * 32 + kc4 * 4;
        size_t i1 = ob1 + j4 * 32 + kc4 * 4;
        *(float4*)(O + i0) = r0;
        *(float4*)(O + i1) = r1;
        ushort4 h0, l0v, h1, l1v;
        h0.x = f2bf(r0.x); l0v.x = f2bf(r0.x - bf2f(h0.x));
        h0.y = f2bf(r0.y); l0v.y = f2bf(r0.y - bf2f(h0.y));
        h0.z = f2bf(r0.z); l0v.z = f2bf(r0.z - bf2f(h0.z));
        h0.w = f2bf(r0.w); l0v.w = f2bf(r0.w - bf2f(h0.w));
        h1.x = f2bf(r1.x); l1v.x = f2bf(r1.x - bf2f(h1.x));
        h1.y = f2bf(r1.y); l1v.y = f2bf(r1.y - bf2f(h1.y));
        h1.z = f2bf(r1.z); l1v.z = f2bf(r1.z - bf2f(h1.z));
        h1.w = f2bf(r1.w); l1v.w = f2bf(r1.w - bf2f(h1.w));
        *(ushort4*)(Ohi + i0) = h0;
        *(ushort4*)(Olo + i0) = l0v;
        *(ushort4*)(Ohi + i1) = h1;
        *(ushort4*)(Olo + i1) = l1v;
    }
}

// ---------------------------------------------------------------------------
// G = silu(G) * U elementwise, fused split-bf16 conversion of the product.
__global__ __launch_bounds__(256) void silu_mul_conv_kernel(
    float* __restrict__ G, const float* __restrict__ U,
    unsigned short* __restrict__ hi, unsigned short* __restrict__ lo, size_t n4) {
    for (size_t i = (size_t)blockIdx.x * 256 + threadIdx.x; i < n4;
         i += (size_t)gridDim.x * 256) {
        float4 g = ((const float4*)G)[i];
        float4 u = ((const float4*)U)[i];
        float4 r;
        r.x = g.x / (1.f + expf(-g.x)) * u.x;
        r.y = g.y / (1.f + expf(-g.y)) * u.y;
        r.z = g.z / (1.f + expf(-g.z)) * u.z;
        r.w = g.w / (1.f + expf(-g.w)) * u.w;
        ((float4*)G)[i] = r;
        ushort4 hv, lv;
        hv.x = f2bf(r.x); lv.x = f2bf(r.x - bf2f(hv.x));
        hv.y = f2bf(r.y); lv.y = f2bf(r.y - bf2f(hv.y));
        hv.z = f2bf(r.z); lv.z = f2bf(r.z - bf2f(hv.z));
        hv.w = f2bf(r.w); lv.w = f2bf(r.w - bf2f(hv.w));
        ((ushort4*)hi)[i] = hv;
        ((ushort4*)lo)[i] = lv;
    }
}

// ---------------------------------------------------------------------------
// Rep extraction + L2 normalize. One block per batch row.
__global__ __launch_bounds__(256) void reps_kernel(const float* __restrict__ Xn,
                                                   const int* __restrict__ mask,
                                                   float* __restrict__ reps) {
    __shared__ float red[256];
    __shared__ int sidx;
    int b = blockIdx.x;
    int ls = 0;
    for (int s = threadIdx.x; s < SS; s += 256) ls += mask[b * SS + s];
    red[threadIdx.x] = (float)ls; __syncthreads();
    for (int s2 = 128; s2 > 0; s2 >>= 1) {
        if (threadIdx.x < s2) red[threadIdx.x] += red[threadIdx.x + s2];
        __syncthreads();
    }
    if (threadIdx.x == 0) {
        int lastsum = 0;
        for (int bb = 0; bb < BB; ++bb) lastsum += mask[bb * SS + SS - 1];
        int lensum = (int)(red[0] + 0.5f);
        sidx = (lastsum == BB) ? (SS - 1) : (lensum - 1);
    }
    __syncthreads();
    const float* xr = Xn + ((size_t)b * SS + sidx) * DDIM;
    float ss = 0.f;
    for (int d = threadIdx.x; d < DDIM; d += 256) { float v = xr[d]; ss += v * v; }
    red[threadIdx.x] = ss; __syncthreads();
    for (int s2 = 128; s2 > 0; s2 >>= 1) {
        if (threadIdx.x < s2) red[threadIdx.x] += red[threadIdx.x + s2];
        __syncthreads();
    }
    float invn = rsqrtf(red[0]);
    for (int d = threadIdx.x; d < DDIM; d += 256)
        reps[(size_t)b * DDIM + d] = xr[d] * invn;
}

// ---------------------------------------------------------------------------
// InfoNCE loss from the two 4x2048 rep matrices.
__global__ __launch_bounds__(256) void loss_kernel(const float* __restrict__ RQ,
                                                   const float* __restrict__ RP,
                                                   float* __restrict__ out) {
    __shared__ float red[256];
    __shared__ float sims[BB][BB];
    for (int p = 0; p < BB * BB; ++p) {
        int i = p / BB, j = p % BB;
        float acc = 0.f;
        for (int d = threadIdx.x; d < DDIM; d += 256)
            acc += RQ[(size_t)i * DDIM + d] * RP[(size_t)j * DDIM + d];
        red[threadIdx.x] = acc; __syncthreads();
        for (int s2 = 128; s2 > 0; s2 >>= 1) {
            if (threadIdx.x < s2) red[threadIdx.x] += red[threadIdx.x + s2];
            __syncthreads();
        }
        if (threadIdx.x == 0) sims[i][j] = red[0] * INV_TEMP;
        __syncthreads();
    }
    if (threadIdx.x == 0) {
        float loss = 0.f;
        for (int i = 0; i < BB; ++i) {
            float m = sims[i][0];
            for (int j = 1; j < BB; ++j) m = fmaxf(m, sims[i][j]);
            float s = 0.f;
            for (int j = 0; j < BB; ++j) s += expf(sims[i][j] - m);
            loss += -(sims[i][i] - m - logf(s));
        }
        out[0] = loss / (float)BB;
    }
}

// ---------------------------------------------------------------------------
extern "C" void kernel_launch(void* const* d_in, const int* in_sizes, int n_in,
                              void* d_out, int out_size, void* d_ws, size_t ws_size,
                              hipStream_t stream) {
    const int* ids_t = (const int*)d_in[0];
    const int* mask_t = (const int*)d_in[1];
    const int* ids_m = (const int*)d_in[2];
    const int* mask_m = (const int*)d_in[3];
    const float* emb = (const float*)d_in[4];
    const float* ln1 = (const float*)d_in[5];
    const float* ln2 = (const float*)d_in[6];
    const float* lnf = (const float*)d_in[7];
    const float* Wq = (const float*)d_in[8];
    const float* Aq = (const float*)d_in[9];
    const float* Bq = (const float*)d_in[10];
    const float* Wk = (const float*)d_in[11];
    const float* Ak = (const float*)d_in[12];
    const float* Bk = (const float*)d_in[13];
    const float* Wv = (const float*)d_in[14];
    const float* Av = (const float*)d_in[15];
    const float* Bv = (const float*)d_in[16];
    const float* Wo = (const float*)d_in[17];
    const float* Ao = (const float*)d_in[18];
    const float* Bo = (const float*)d_in[19];
    const float* Wg = (const float*)d_in[20];
    const float* Ag = (const float*)d_in[21];
    const float* Bg = (const float*)d_in[22];
    const float* Wu = (const float*)d_in[23];
    const float* Au = (const float*)d_in[24];
    const float* Bu = (const float*)d_in[25];
    const float* Wd = (const float*)d_in[26];
    const float* Ad = (const float*)d_in[27];
    const float* Bd = (const float*)d_in[28];

    float* ws = (float*)d_ws;
    float* h    = ws;
    float* x    = ws + 1 * BSD;
    float* qb   = ws + 2 * BSD;
    float* kb   = ws + 3 * BSD;
    float* vb   = ws + 4 * BSD;
    float* ob   = ws + 5 * BSD;
    float* proj = ws + 6 * BSD;
    float* gbuf = ws + 7 * BSD;
    float* ubuf = gbuf + BSFF;
    float* T    = ubuf + BSFF;
    float* repsq = T + (size_t)BSROWS * 16;
    float* repsp = repsq + BB * DDIM;
    float2* rtab = (float2*)(repsp + BB * DDIM);
    unsigned short* xhi = (unsigned short*)(rtab + SS * 64);
    unsigned short* xlo = xhi + MAXXE;
    unsigned short* whi = xlo + MAXXE;
    unsigned short* wlo = whi + MAXWE;

    hipLaunchKernelGGL(rope_table_kernel, dim3(SS), dim3(64), 0, stream, rtab);

    auto mfma_proj = [&](const float* Wf, int K, int M, float* C) {
        hipLaunchKernelGGL(wconvt_kernel, dim3(M / 32, K / 32), dim3(256), 0, stream,
                           Wf, whi, wlo, K, M);
        hipLaunchKernelGGL(gemm_mfma_kernel, dim3(M / 128, BSROWS / 128), dim3(256),
                           0, stream, xhi, xlo, whi, wlo, C, K, M);
    };
    auto lora_tail = [&](const float* Xf, const float* Am, const float* Bm,
                         float* C, int K, int M) {
        hipLaunchKernelGGL(gemm16_kernel, dim3(BSROWS), dim3(256), 0, stream, Xf, Am, T, K);
        hipLaunchKernelGGL(lora_add_kernel, dim3(BSROWS), dim3(256), 0, stream, C, T, Bm, M);
    };
    auto lora_tail_res = [&](const float* Xf, const float* Am, const float* Bm,
                             float* Hb, float* C, int K, int M) {
        hipLaunchKernelGGL(gemm16_kernel, dim3(BSROWS), dim3(256), 0, stream, Xf, Am, T, K);
        hipLaunchKernelGGL(lora_add_residual_kernel, dim3(BSROWS), dim3(256), 0,
                           stream, Hb, C, T, Bm, M);
    };

    for (int enc = 0; enc < 2; ++enc) {
        const int* ids = enc == 0 ? ids_t : ids_m;
        const int* mask = enc == 0 ? mask_t : mask_m;
        float* reps = enc == 0 ? repsq : repsp;

        hipLaunchKernelGGL(embed_kernel, dim3(BSROWS), dim3(256), 0, stream, ids, emb, h);

        for (int l = 0; l < LNUM; ++l) {
            size_t oDD = (size_t)l * DDIM * DDIM;
            size_t oDR = (size_t)l * DDIM * RNK;
            size_t oRD = (size_t)l * RNK * DDIM;
            size_t oDF = (size_t)l * DDIM * FFDIM;
            size_t oRF = (size_t)l * RNK * FFDIM;
            size_t oFD = (size_t)l * FFDIM * DDIM;
            size_t oFR = (size_t)l * FFDIM * RNK;

            // attn block: rmsnorm (+fused conv), Q/K/V projections
            hipLaunchKernelGGL(rmsnorm_conv_kernel, dim3(BSROWS), dim3(256), 0, stream,
                               h, ln1 + (size_t)l * DDIM, x, xhi, xlo);
            mfma_proj(Wq + oDD, DDIM, DDIM, qb);
            lora_tail(x, Aq + oDR, Bq + oRD, qb, DDIM, DDIM);
            mfma_proj(Wk + oDD, DDIM, DDIM, kb);
            lora_tail(x, Ak + oDR, Bk + oRD, kb, DDIM, DDIM);
            mfma_proj(Wv + oDD, DDIM, DDIM, vb);
            lora_tail(x, Av + oDR, Bv + oRD, vb, DDIM, DDIM);

            hipLaunchKernelGGL(rope_kernel, dim3(BB * SS * HNUM, 2), dim3(64), 0,
                               stream, qb, kb, rtab);
            // fattn writes ob AND its split-bf16 (xhi,xlo) for the Wo GEMM
            hipLaunchKernelGGL(fattn_kernel, dim3(BB * HNUM * (SS / 32)), dim3(128),
                               0, stream, qb, kb, vb, mask, ob, xhi, xlo);

            mfma_proj(Wo + oDD, DDIM, DDIM, proj);
            lora_tail_res(ob, Ao + oDR, Bo + oRD, h, proj, DDIM, DDIM);

            // FFN block
            hipLaunchKernelGGL(rmsnorm_conv_kernel, dim3(BSROWS), dim3(256), 0, stream,
                               h, ln2 + (size_t)l * DDIM, x, xhi, xlo);
            mfma_proj(Wg + oDF, DDIM, FFDIM, gbuf);
            lora_tail(x, Ag + oDR, Bg + oRF, gbuf, DDIM, FFDIM);
            mfma_proj(Wu + oDF, DDIM, FFDIM, ubuf);
            lora_tail(x, Au + oDR, Bu + oRF, ubuf, DDIM, FFDIM);

            hipLaunchKernelGGL(silu_mul_conv_kernel, dim3(2048), dim3(256), 0, stream,
                               gbuf, ubuf, xhi, xlo, BSFF / 4);
            mfma_proj(Wd + oFD, FFDIM, DDIM, proj);
            lora_tail_res(gbuf, Ad + oFR, Bd + oRD, h, proj, FFDIM, DDIM);
        }
        hipLaunchKernelGGL(rmsnorm_kernel, dim3(BSROWS), dim3(256), 0, stream, h, lnf, x);
        hipLaunchKernelGGL(reps_kernel, dim3(BB), dim3(256), 0, stream, x, mask, reps);
    }
    hipLaunchKernelGGL(loss_kernel, dim3(1), dim3(256), 0, stream,
                       repsq, repsp, (float*)d_out);
}